// Round 9
// baseline (242.254 us; speedup 1.0000x reference)
//
#include <hip/hip_runtime.h>
#include <stdint.h>

#define N_V   4096
#define T_PER 4
#define NT    16384
#define D_K   256
#define SCALE 10.0f   // 1/temperature
#define LOG2E 1.44269504088896340736f
#define LN2   0.69314718055994530942f

#if defined(__has_builtin)
#if __has_builtin(__builtin_amdgcn_exp2f)
#define EXP2F(x) __builtin_amdgcn_exp2f(x)
#endif
#endif
#ifndef EXP2F
#define EXP2F(x) exp2f(x)
#endif

typedef __bf16 bf16x8 __attribute__((ext_vector_type(8)));
typedef float  f32x4  __attribute__((ext_vector_type(4)));

__device__ __forceinline__ unsigned short f2bf(float f) {
  uint32_t u = __float_as_uint(f);
  u = (u + 0x7fffu + ((u >> 16) & 1u)) >> 16;   // RNE
  return (unsigned short)u;
}

// ---------------- A: fused convert + diagonal dots (reads v,t exactly once) ---------------
// A-side bf16 carries SCALE*LOG2E so GEMM scores come out in log2 domain.
__global__ void k_prep(const float* __restrict__ v, const float* __restrict__ t,
                       unsigned short* __restrict__ Abf, unsigned short* __restrict__ Bbf,
                       float* __restrict__ thr, float* __restrict__ nom,
                       float* __restrict__ out) {
  const int tid = threadIdx.x, l = tid & 63, w = tid >> 6;
  const int i = blockIdx.x * 4 + w;            // one wave per video
  if (blockIdx.x == 0 && tid < 5) out[tid] = 0.0f;
  const float AS = SCALE * LOG2E;

  float4 a = ((const float4*)(v + (size_t)i * D_K))[l];
  ushort4 oa;
  oa.x = f2bf(a.x * AS); oa.y = f2bf(a.y * AS);
  oa.z = f2bf(a.z * AS); oa.w = f2bf(a.w * AS);
  ((ushort4*)(Abf + (size_t)i * D_K))[l] = oa;

  float tv[T_PER];
#pragma unroll
  for (int tt = 0; tt < T_PER; ++tt) {
    float4 b = ((const float4*)(t + (size_t)(i * T_PER + tt) * D_K))[l];
    ushort4 ob;
    ob.x = f2bf(b.x); ob.y = f2bf(b.y); ob.z = f2bf(b.z); ob.w = f2bf(b.w);
    ((ushort4*)(Bbf + (size_t)(i * T_PER + tt) * D_K))[l] = ob;
    float d = a.x * b.x + a.y * b.y + a.z * b.z + a.w * b.w;
#pragma unroll
    for (int s = 1; s < 64; s <<= 1) d += __shfl_xor(d, s);
    tv[tt] = d * SCALE;                        // natural-domain score
  }
  if (l == 0) {
    ((float4*)thr)[i] = make_float4(tv[0] * LOG2E, tv[1] * LOG2E,
                                    tv[2] * LOG2E, tv[3] * LOG2E);
    float m = fmaxf(fmaxf(tv[0], tv[1]), fmaxf(tv[2], tv[3]));
    float e = __expf(tv[0] - m) + __expf(tv[1] - m) + __expf(tv[2] - m) + __expf(tv[3] - m);
    nom[i] = m + __logf(e);
  }
}

// ---------------- B: r7 K-loop + single-exp, low-shfl epilogue -----------------------------
// Block = 64 rows x 256 cols (r7's best-measured structure, 126us). Epilogue rework:
//   * block-shared max Mb + clamp(-60): ONE exp per score serves row and col sums.
//     Clamp guarantees every partial sum > 0 (no log(0) — the r2/r3 bug) and contributes
//     <= 2^-46 relative error after the LSE merge (each clamped term <= 2^-60, M_partial
//     <= M_final at merge time).
//   * row reduction via LDS transpose (stride 84 floats, bank-spread) instead of 128
//     serialized ds_swizzle shfl trees per wave (LDS pipe was co-saturated in r8).
//   * A-tile LDS reused (phased, barriers) for the transpose buffers -> 34 KB, 4 blocks/CU.
__device__ __forceinline__ void gld16(const void* g, void* l) {
  __builtin_amdgcn_global_load_lds((const __attribute__((address_space(1))) void*)g,
                                   (__attribute__((address_space(3))) void*)l,
                                   16, 0, 0);
}

__global__ __launch_bounds__(256) void k_gemm(
    const unsigned short* __restrict__ Abf, const unsigned short* __restrict__ Bbf,
    const float* __restrict__ thr,
    float* __restrict__ pmax, float* __restrict__ psum, uint4* __restrict__ pcnt,
    float* __restrict__ cmax, float* __restrict__ csum) {
  __shared__ __align__(16) char pool[32768];   // As during K-loop; transpose buf after
  __shared__ float4 thrS[64];
  __shared__ float  Ms[4];
  unsigned short* As = (unsigned short*)pool;

  const int ct = blockIdx.x, rt = blockIdx.y;
  const int row0 = rt * 64, col0 = ct * 256;
  const int tid = threadIdx.x;
  const int l = tid & 63, w = tid >> 6;
  const int quad = l >> 4, nl = l & 15;

  if (tid < 64) thrS[tid] = ((const float4*)thr)[row0 + tid];

  // stage A once (r7-verbatim): 32 groups of 1024 B, XOR-swizzled
  const int lr = l >> 3, lc7 = l & 7, sc = lc7 ^ lr;
#pragma unroll
  for (int it = 0; it < 8; ++it) {
    int g = w * 8 + it;
    int rs = g >> 2, ks = g & 3;
    const unsigned short* ga = Abf + (size_t)(row0 + rs * 8 + lr) * D_K + ks * 64 + sc * 8;
    gld16(ga, (char*)As + g * 1024);
  }

  f32x4 acc[4][4];
#pragma unroll
  for (int i = 0; i < 4; ++i)
#pragma unroll
    for (int j = 0; j < 4; ++j) acc[i][j] = {0.f, 0.f, 0.f, 0.f};

  const unsigned short* pB[4];
#pragma unroll
  for (int j = 0; j < 4; ++j)
    pB[j] = Bbf + (size_t)(col0 + w * 64 + j * 16 + nl) * D_K + quad * 8;

  __syncthreads();   // publishes As (compiler drains vmcnt before barrier)

  bf16x8 bv[2][4];
#pragma unroll
  for (int j = 0; j < 4; ++j) bv[0][j] = *(const bf16x8*)(pB[j]);

#pragma unroll
  for (int c = 0; c < 8; ++c) {                 // 8 chunks of K=32, B dbuf from global/L2
    const int cur = c & 1;
    if (c < 7) {
#pragma unroll
      for (int j = 0; j < 4; ++j)
        bv[cur ^ 1][j] = *(const bf16x8*)(pB[j] + (c + 1) * 32);
    }
    bf16x8 af[4];
#pragma unroll
    for (int i = 0; i < 4; ++i) {
      int r = i * 16 + nl;
      int rb = r & 7;
      int grp = (r >> 3) * 4 + (c >> 1);
      int cc = ((((c & 1) << 2) | quad) ^ rb);
      af[i] = *(const bf16x8*)((const char*)As + grp * 1024 + (rb * 8 + cc) * 16);
    }
#pragma unroll
    for (int i = 0; i < 4; ++i)
#pragma unroll
      for (int j = 0; j < 4; ++j)
        acc[i][j] = __builtin_amdgcn_mfma_f32_16x16x32_bf16(af[i], bv[cur][j],
                                                            acc[i][j], 0, 0, 0);
  }

  // ================= epilogue (scores in log2 domain) =================
  // C/D layout: col = nl, row = quad*4 + reg.

  // 1. block max
  float m = acc[0][0][0];
#pragma unroll
  for (int i = 0; i < 4; ++i)
#pragma unroll
    for (int j = 0; j < 4; ++j)
#pragma unroll
      for (int r = 0; r < 4; ++r) m = fmaxf(m, acc[i][j][r]);
#pragma unroll
  for (int d = 1; d < 64; d <<= 1) m = fmaxf(m, __shfl_xor(m, d));
  if (l == 0) Ms[w] = m;
  __syncthreads();                       // B1: Ms visible; As dead (acc in registers)
  const float Mb = fmaxf(fmaxf(Ms[0], Ms[1]), fmaxf(Ms[2], Ms[3]));

  // 2. one exp per score (clamped) + rank counts + in-lane row/col accumulation
  float    rowe[4][4];
  uint32_t rcntp[4][4];
  float    cole[4] = {0.f, 0.f, 0.f, 0.f};
#pragma unroll
  for (int i = 0; i < 4; ++i)
#pragma unroll
    for (int r = 0; r < 4; ++r) {
      float4 th = thrS[i * 16 + quad * 4 + r];
      float es = 0.f;
      uint32_t cc = 0;
#pragma unroll
      for (int j = 0; j < 4; ++j) {
        float s = acc[i][j][r];
        float e = EXP2F(fmaxf(s - Mb, -60.0f));
        es += e;
        cole[j] += e;
        cc += (uint32_t)(s > th.x);
        cc += (uint32_t)(s > th.y) << 8;
        cc += (uint32_t)(s > th.z) << 16;
        cc += (uint32_t)(s > th.w) << 24;
      }
      rowe[i][r] = es;
      rcntp[i][r] = cc;
    }

  // 3. col partials: cross-quad sum (2 shfls), direct global write
#pragma unroll
  for (int j = 0; j < 4; ++j) {
    float t = cole[j];
    t += __shfl_xor(t, 16);
    t += __shfl_xor(t, 32);
    if (quad == 0) {
      size_t gi = (size_t)rt * NT + col0 + w * 64 + j * 16 + nl;
      cmax[gi] = Mb; csum[gi] = t;
    }
  }

  // 4. row e-sums via LDS transpose (stride 84 floats: bank-spread, 16B-aligned rows)
  float* rowEb = (float*)pool;
#pragma unroll
  for (int i = 0; i < 4; ++i)
#pragma unroll
    for (int r = 0; r < 4; ++r)
      rowEb[(i * 16 + quad * 4 + r) * 84 + w * 16 + nl] = rowe[i][r];
  __syncthreads();                       // B2
  if (tid < 64) {
    const float4* p4 = (const float4*)(rowEb + tid * 84);
    float s = 0.f;
#pragma unroll
    for (int q = 0; q < 16; ++q) {
      float4 vv = p4[q];
      s += (vv.x + vv.y) + (vv.z + vv.w);
    }
    size_t gi = (size_t)ct * N_V + row0 + tid;
    pmax[gi] = Mb; psum[gi] = s;
  }
  __syncthreads();                       // B3: e-reads done, reuse pool for counts

  // 5. row counts via the same transpose; packed-SIMD reduce (fields <= 256, fit 16-bit)
  uint32_t* cntB = (uint32_t*)pool;
#pragma unroll
  for (int i = 0; i < 4; ++i)
#pragma unroll
    for (int r = 0; r < 4; ++r)
      cntB[(i * 16 + quad * 4 + r) * 84 + w * 16 + nl] = rcntp[i][r];
  __syncthreads();                       // B4
  if (tid < 64) {
    const uint4* p4 = (const uint4*)(cntB + tid * 84);
    uint32_t lo = 0, hi = 0;
#pragma unroll
    for (int q = 0; q < 16; ++q) {
      uint4 vv = p4[q];
      lo += vv.x & 0x00ff00ffu; hi += (vv.x >> 8) & 0x00ff00ffu;
      lo += vv.y & 0x00ff00ffu; hi += (vv.y >> 8) & 0x00ff00ffu;
      lo += vv.z & 0x00ff00ffu; hi += (vv.z >> 8) & 0x00ff00ffu;
      lo += vv.w & 0x00ff00ffu; hi += (vv.w >> 8) & 0x00ff00ffu;
    }
    size_t gi = (size_t)ct * N_V + row0 + tid;
    pcnt[gi] = make_uint4(lo & 0xffffu, hi & 0xffffu, lo >> 16, hi >> 16);
  }
}

// ---------------- C: fused col-reduce + row-reduce + loss/metrics --------------------------
// Block cb owns cols [cb*128, cb*128+128) AND rows [cb*32, cb*32+32): row r's needed col
// results (cols 4r..4r+3) are exactly in-range -> no grid sync, col results stay in LDS.
__global__ void k_post(const float* __restrict__ pmax, const float* __restrict__ psum,
                       const uint4* __restrict__ pcnt,
                       const float* __restrict__ cmax, const float* __restrict__ csum,
                       const float* __restrict__ nom, float* __restrict__ out) {
  __shared__ float Cm[2][128], Cs[2][128];
  __shared__ float colmL[128], colsL[128];
  const int cb = blockIdx.x, tid = threadIdx.x;

  // cols: 64 partials each, coalesced
  {
    int c = tid & 127, h = tid >> 7;
    int col = cb * 128 + c;
    float M = -3.0e38f, S = 0.f;
    for (int k = 0; k < 32; ++k) {
      size_t idx = (size_t)(h * 32 + k) * NT + col;
      float mm = cmax[idx], ss = csum[idx];
      float nM = fmaxf(M, mm);
      S = S * EXP2F(M - nM) + ss * EXP2F(mm - nM);
      M = nM;
    }
    Cm[h][c] = M; Cs[h][c] = S;
  }
  __syncthreads();
  if (tid < 128) {
    float M0 = Cm[0][tid], S0 = Cs[0][tid];
    float M1 = Cm[1][tid], S1 = Cs[1][tid];
    float Mx = fmaxf(M0, M1);
    colmL[tid] = Mx;
    colsL[tid] = S0 * EXP2F(M0 - Mx) + S1 * EXP2F(M1 - Mx);
  }
  __syncthreads();

  // rows: 32 rows x 64 partials, then final loss/metrics
  if (tid < 32) {
    int row = cb * 32 + tid;
    float M = -3.0e38f, S = 0.f;
    uint32_t c0 = 0, c1 = 0, c2 = 0, c3 = 0;
    for (int k = 0; k < 64; ++k) {
      size_t idx = (size_t)k * N_V + row;
      float mm = pmax[idx], ss = psum[idx];
      uint4 cc = pcnt[idx];
      float nM = fmaxf(M, mm);
      S = S * EXP2F(M - nM) + ss * EXP2F(mm - nM);
      M = nM;
      c0 += cc.x; c1 += cc.y; c2 += cc.z; c3 += cc.w;
    }
    float cm0 = colmL[tid * 4 + 0], cm1 = colmL[tid * 4 + 1];
    float cm2 = colmL[tid * 4 + 2], cm3 = colmL[tid * 4 + 3];
    float cs0 = colsL[tid * 4 + 0], cs1 = colsL[tid * 4 + 1];
    float cs2 = colsL[tid * 4 + 2], cs3 = colsL[tid * 4 + 3];
    float Mp = fmaxf(M, fmaxf(fmaxf(cm0, cm1), fmaxf(cm2, cm3)));
    float tot = S * EXP2F(M - Mp)
              + cs0 * EXP2F(cm0 - Mp) + cs1 * EXP2F(cm1 - Mp)
              + cs2 * EXP2F(cm2 - Mp) + cs3 * EXP2F(cm3 - Mp);
    float ll = LN2 * (Mp + __log2f(tot)) - nom[row];
    float ar  = (float)(c0 + c1 + c2 + c3) * 0.25f;
    float r1  = (float)((c0 < 1u) + (c1 < 1u) + (c2 < 1u) + (c3 < 1u)) * 0.25f;
    float r5  = (float)((c0 < 5u) + (c1 < 5u) + (c2 < 5u) + (c3 < 5u)) * 0.25f;
    float r10 = (float)((c0 < 10u) + (c1 < 10u) + (c2 < 10u) + (c3 < 10u)) * 0.25f;
    float vals[5] = {ll, r1, r5, r10, ar};
#pragma unroll
    for (int k = 0; k < 5; ++k) {
      float vv = vals[k];
#pragma unroll
      for (int d = 1; d < 32; d <<= 1) vv += __shfl_xor(vv, d);
      if (tid == 0) atomicAdd(&out[k], vv * (1.0f / N_V));
    }
  }
}

extern "C" void kernel_launch(void* const* d_in, const int* in_sizes, int n_in,
                              void* d_out, int out_size, void* d_ws, size_t ws_size,
                              hipStream_t stream) {
  const float* v = (const float*)d_in[0];
  const float* t = (const float*)d_in[1];
  char* p = (char*)d_ws;
  unsigned short* Abf = (unsigned short*)p; p += (size_t)N_V * D_K * 2;
  unsigned short* Bbf = (unsigned short*)p; p += (size_t)NT * D_K * 2;
  float* thr  = (float*)p;    p += (size_t)N_V * 4 * 4;
  float* nom  = (float*)p;    p += (size_t)N_V * 4;
  float* pmax = (float*)p;    p += (size_t)64 * N_V * 4;
  float* psum = (float*)p;    p += (size_t)64 * N_V * 4;
  uint4* pcnt = (uint4*)p;    p += (size_t)64 * N_V * 16;
  float* cmaxp = (float*)p;   p += (size_t)64 * NT * 4;
  float* csump = (float*)p;   p += (size_t)64 * NT * 4;
  // total ws: ~24 MB

  k_prep<<<N_V / 4, 256, 0, stream>>>(v, t, Abf, Bbf, thr, nom, (float*)d_out);
  dim3 g(NT / 256, N_V / 64);                     // ct x rt = 64 x 64
  k_gemm<<<g, 256, 0, stream>>>(Abf, Bbf, thr, pmax, psum, pcnt, cmaxp, csump);
  k_post<<<NT / 128, 256, 0, stream>>>(pmax, psum, pcnt, cmaxp, csump, nom, (float*)d_out);
}

// Round 10
// 219.346 us; speedup vs baseline: 1.1044x; 1.1044x over previous
//
#include <hip/hip_runtime.h>
#include <hip/hip_fp16.h>
#include <stdint.h>

#define N_V   4096
#define T_PER 4
#define NT    16384
#define D_K   256
#define SCALE 10.0f   // 1/temperature
#define LOG2E 1.44269504088896340736f
#define LN2   0.69314718055994530942f

#if defined(__has_builtin)
#if __has_builtin(__builtin_amdgcn_exp2f)
#define EXP2F(x) __builtin_amdgcn_exp2f(x)
#endif
#endif
#ifndef EXP2F
#define EXP2F(x) exp2f(x)
#endif

typedef __bf16 bf16x8 __attribute__((ext_vector_type(8)));
typedef float  f32x4  __attribute__((ext_vector_type(4)));

__device__ __forceinline__ unsigned short f2bf(float f) {
  uint32_t u = __float_as_uint(f);
  u = (u + 0x7fffu + ((u >> 16) & 1u)) >> 16;   // RNE
  return (unsigned short)u;
}

// ---------------- A: fused convert + diagonal dots (reads v,t exactly once) ---------------
// A-side bf16 carries SCALE*LOG2E so GEMM scores come out in log2 domain.
__global__ void k_prep(const float* __restrict__ v, const float* __restrict__ t,
                       unsigned short* __restrict__ Abf, unsigned short* __restrict__ Bbf,
                       float* __restrict__ thr, float* __restrict__ nom,
                       float* __restrict__ out) {
  const int tid = threadIdx.x, l = tid & 63, w = tid >> 6;
  const int i = blockIdx.x * 4 + w;            // one wave per video
  if (blockIdx.x == 0 && tid < 5) out[tid] = 0.0f;
  const float AS = SCALE * LOG2E;

  float4 a = ((const float4*)(v + (size_t)i * D_K))[l];
  ushort4 oa;
  oa.x = f2bf(a.x * AS); oa.y = f2bf(a.y * AS);
  oa.z = f2bf(a.z * AS); oa.w = f2bf(a.w * AS);
  ((ushort4*)(Abf + (size_t)i * D_K))[l] = oa;

  float tv[T_PER];
#pragma unroll
  for (int tt = 0; tt < T_PER; ++tt) {
    float4 b = ((const float4*)(t + (size_t)(i * T_PER + tt) * D_K))[l];
    ushort4 ob;
    ob.x = f2bf(b.x); ob.y = f2bf(b.y); ob.z = f2bf(b.z); ob.w = f2bf(b.w);
    ((ushort4*)(Bbf + (size_t)(i * T_PER + tt) * D_K))[l] = ob;
    float d = a.x * b.x + a.y * b.y + a.z * b.z + a.w * b.w;
#pragma unroll
    for (int s = 1; s < 64; s <<= 1) d += __shfl_xor(d, s);
    tv[tt] = d * SCALE;                        // natural-domain score
  }
  if (l == 0) {
    ((float4*)thr)[i] = make_float4(tv[0] * LOG2E, tv[1] * LOG2E,
                                    tv[2] * LOG2E, tv[3] * LOG2E);
    float m = fmaxf(fmaxf(tv[0], tv[1]), fmaxf(tv[2], tv[3]));
    float e = __expf(tv[0] - m) + __expf(tv[1] - m) + __expf(tv[2] - m) + __expf(tv[3] - m);
    nom[i] = m + __logf(e);
  }
}

// ---------------- B: r7 K-loop; epilogue = exact counts + fp16 score store -----------------
// Counts computed from fp32 acc (bit-identical to r7 -> metrics outputs stay exact).
// LSE epilogue moved to k_tile: scores stored fp16 (log2 domain, |s|<~1300 fits; +-0.64
// log2 rounding affects only the loss, ~+-0.05 after the mean — threshold is 163.84).
__device__ __forceinline__ void gld16(const void* g, void* l) {
  __builtin_amdgcn_global_load_lds((const __attribute__((address_space(1))) void*)g,
                                   (__attribute__((address_space(3))) void*)l,
                                   16, 0, 0);
}

__global__ __launch_bounds__(256) void k_gemm(
    const unsigned short* __restrict__ Abf, const unsigned short* __restrict__ Bbf,
    const float* __restrict__ thr,
    unsigned short* __restrict__ S, uint4* __restrict__ pcnt) {
  // pool: As staging (32768 B) during K-loop; fp16 score tile [64][264] (33792 B) after
  __shared__ __align__(16) char pool[64 * 264 * 2];
  __shared__ float4   thrS[64];
  __shared__ uint32_t rowCw[4][64];
  unsigned short* As = (unsigned short*)pool;

  const int ct = blockIdx.x, rt = blockIdx.y;
  const int row0 = rt * 64, col0 = ct * 256;
  const int tid = threadIdx.x;
  const int l = tid & 63, w = tid >> 6;
  const int quad = l >> 4, nl = l & 15;

  if (tid < 64) thrS[tid] = ((const float4*)thr)[row0 + tid];

  // stage A once (r7-verbatim): 32 groups of 1024 B, XOR-swizzled
  const int lr = l >> 3, lc7 = l & 7, sc = lc7 ^ lr;
#pragma unroll
  for (int it = 0; it < 8; ++it) {
    int g = w * 8 + it;
    int rs = g >> 2, ks = g & 3;
    const unsigned short* ga = Abf + (size_t)(row0 + rs * 8 + lr) * D_K + ks * 64 + sc * 8;
    gld16(ga, (char*)As + g * 1024);
  }

  f32x4 acc[4][4];
#pragma unroll
  for (int i = 0; i < 4; ++i)
#pragma unroll
    for (int j = 0; j < 4; ++j) acc[i][j] = {0.f, 0.f, 0.f, 0.f};

  const unsigned short* pB[4];
#pragma unroll
  for (int j = 0; j < 4; ++j)
    pB[j] = Bbf + (size_t)(col0 + w * 64 + j * 16 + nl) * D_K + quad * 8;

  __syncthreads();   // publishes As

  bf16x8 bv[2][4];
#pragma unroll
  for (int j = 0; j < 4; ++j) bv[0][j] = *(const bf16x8*)(pB[j]);

#pragma unroll
  for (int c = 0; c < 8; ++c) {                 // 8 chunks of K=32, B dbuf from global/L2
    const int cur = c & 1;
    if (c < 7) {
#pragma unroll
      for (int j = 0; j < 4; ++j)
        bv[cur ^ 1][j] = *(const bf16x8*)(pB[j] + (c + 1) * 32);
    }
    bf16x8 af[4];
#pragma unroll
    for (int i = 0; i < 4; ++i) {
      int r = i * 16 + nl;
      int rb = r & 7;
      int grp = (r >> 3) * 4 + (c >> 1);
      int cc = ((((c & 1) << 2) | quad) ^ rb);
      af[i] = *(const bf16x8*)((const char*)As + grp * 1024 + (rb * 8 + cc) * 16);
    }
#pragma unroll
    for (int i = 0; i < 4; ++i)
#pragma unroll
      for (int j = 0; j < 4; ++j)
        acc[i][j] = __builtin_amdgcn_mfma_f32_16x16x32_bf16(af[i], bv[cur][j],
                                                            acc[i][j], 0, 0, 0);
  }

  // ===== epilogue =====  (C/D layout: col = nl, row = quad*4 + reg)
  __syncthreads();   // B1: all As reads done -> pool reusable

  // exact fp32 rank counts (r7 logic): packed 4x8-bit, tree over 16 nl-lanes
#pragma unroll
  for (int i = 0; i < 4; ++i)
#pragma unroll
    for (int r = 0; r < 4; ++r) {
      float4 th = thrS[i * 16 + quad * 4 + r];
      uint32_t cc = 0;
#pragma unroll
      for (int j = 0; j < 4; ++j) {
        float s = acc[i][j][r];
        cc += (uint32_t)(s > th.x);
        cc += (uint32_t)(s > th.y) << 8;
        cc += (uint32_t)(s > th.z) << 16;
        cc += (uint32_t)(s > th.w) << 24;
      }
#pragma unroll
      for (int d = 1; d < 16; d <<= 1) cc += __shfl_xor(cc, d);
      if (nl == 0) rowCw[w][i * 16 + quad * 4 + r] = cc;   // fields <= 64, no overflow
    }

  // fp16 scores into pool, row stride 264 shorts (528 B; inter-quad bank spread)
#pragma unroll
  for (int i = 0; i < 4; ++i)
#pragma unroll
    for (int j = 0; j < 4; ++j)
#pragma unroll
      for (int r = 0; r < 4; ++r) {
        int row = i * 16 + quad * 4 + r;
        int col = w * 64 + j * 16 + nl;
        ((__half*)pool)[row * 264 + col] = __float2half(acc[i][j][r]);
      }
  __syncthreads();   // B2: rowCw + score tile visible

  // combine 4 col-strips of counts -> uint4 (4x64 = 256 would overflow 8-bit fields)
  if (tid < 64) {
    uint32_t c0 = 0, c1 = 0, c2 = 0, c3 = 0;
#pragma unroll
    for (int ww = 0; ww < 4; ++ww) {
      uint32_t cc = rowCw[ww][tid];
      c0 += cc & 0xffu; c1 += (cc >> 8) & 0xffu;
      c2 += (cc >> 16) & 0xffu; c3 += cc >> 24;
    }
    pcnt[(size_t)ct * N_V + row0 + tid] = make_uint4(c0, c1, c2, c3);
  }

  // coalesced fp16 store: per iter each half-wave covers one full 512B row-segment
  const int cch = l & 31, hh = l >> 5;
#pragma unroll
  for (int rr = 0; rr < 8; ++rr) {
    int row = w * 16 + rr * 2 + hh;
    uint4 v4 = *(const uint4*)(pool + row * 528 + cch * 16);
    *(uint4*)((char*)S + ((size_t)(row0 + row) * NT + col0) * 2 + cch * 16) = v4;
  }
}

// ---------------- C: streaming tile epilogue (row/col LSE partials) ------------------------
// 64x128 fp16 tile -> fp32 LDS [64][129] (odd stride: row pass lanes=rows conflict-free,
// col pass lanes=cols conflict-free). High occupancy (no AGPRs) hides exp/LDS latency.
__global__ __launch_bounds__(256) void k_tile(
    const unsigned short* __restrict__ S,
    float* __restrict__ pmax, float* __restrict__ psum,
    float* __restrict__ cmax, float* __restrict__ csum) {
  __shared__ float T_[64 * 129];               // 33024 B
  __shared__ float Cm[2][128], Cs[2][128];
  __shared__ float Rm[4][64], Re[4][64];

  const int ct = blockIdx.x, rt = blockIdx.y;
  const int c0 = ct * 128, r0 = rt * 64;
  const int tid = threadIdx.x;
  const int l = tid & 63, w = tid >> 6;

  // stage: wave w rows it*4+w; lane l loads 2 fp16 at col 2l (coalesced 256B/row)
#pragma unroll
  for (int it = 0; it < 16; ++it) {
    int row = it * 4 + w;
    uint32_t d = *(const uint32_t*)(S + (size_t)(r0 + row) * NT + c0 + 2 * l);
    __half2 h2 = *(__half2*)&d;
    float2 f = __half22float2(h2);
    T_[row * 129 + 2 * l]     = f.x;
    T_[row * 129 + 2 * l + 1] = f.y;
  }
  __syncthreads();

  // col pass: thread owns col (t&127), half h = t>>7 (rows h*32..+32)
  {
    int cc = tid & 127, h = tid >> 7;
    float m = -3.0e38f;
#pragma unroll
    for (int k = 0; k < 32; ++k) m = fmaxf(m, T_[(h * 32 + k) * 129 + cc]);
    float e = 0.f;
#pragma unroll
    for (int k = 0; k < 32; ++k) e += EXP2F(T_[(h * 32 + k) * 129 + cc] - m);
    Cm[h][cc] = m; Cs[h][cc] = e;
  }

  // row pass 1: thread owns row (t&63), quarter q = t>>6 (cols q*32..+32): quarter max
  const int rr = tid & 63, q = tid >> 6;
  {
    float m = -3.0e38f;
#pragma unroll
    for (int k = 0; k < 32; ++k) m = fmaxf(m, T_[rr * 129 + q * 32 + k]);
    Rm[q][rr] = m;
  }
  __syncthreads();

  // col merge + write ([rt][col] layout)
  if (tid < 128) {
    float M0 = Cm[0][tid], M1 = Cm[1][tid];
    float Mx = fmaxf(M0, M1);
    float Sx = Cs[0][tid] * EXP2F(M0 - Mx) + Cs[1][tid] * EXP2F(M1 - Mx);
    size_t gi = (size_t)rt * NT + c0 + tid;
    cmax[gi] = Mx; csum[gi] = Sx;
  }

  // row pass 2: full-tile row max, quarter exp-sums (max term = 1 -> sum >= 1, no log(0))
  {
    float Mr = fmaxf(fmaxf(Rm[0][rr], Rm[1][rr]), fmaxf(Rm[2][rr], Rm[3][rr]));
    float e = 0.f;
#pragma unroll
    for (int k = 0; k < 32; ++k) e += EXP2F(T_[rr * 129 + q * 32 + k] - Mr);
    Re[q][rr] = e;
  }
  __syncthreads();
  if (tid < 64) {
    float Mr = fmaxf(fmaxf(Rm[0][tid], Rm[1][tid]), fmaxf(Rm[2][tid], Rm[3][tid]));
    float e = Re[0][tid] + Re[1][tid] + Re[2][tid] + Re[3][tid];
    size_t gi = (size_t)ct * N_V + r0 + tid;
    pmax[gi] = Mr; psum[gi] = e;
  }
}

// ---------------- D: merge partials + loss/metrics -----------------------------------------
// Block cb owns cols [cb*128, +128) and rows [cb*32, +32); row r needs cols 4r..4r+3 which
// lie exactly in-range -> col results stay in LDS, no grid sync.
__global__ void k_post(const float* __restrict__ pmax, const float* __restrict__ psum,
                       const uint4* __restrict__ pcnt,
                       const float* __restrict__ cmax, const float* __restrict__ csum,
                       const float* __restrict__ nom, float* __restrict__ out) {
  __shared__ float Qm[2][128], Qs[2][128];
  __shared__ float colmL[128], colsL[128];
  const int cb = blockIdx.x, tid = threadIdx.x;

  // cols: 64 partials each (rt tiles), coalesced
  {
    int c = tid & 127, h = tid >> 7;
    size_t col = (size_t)cb * 128 + c;
    float M = -3.0e38f, Ssum = 0.f;
    for (int k = 0; k < 32; ++k) {
      size_t idx = (size_t)(h * 32 + k) * NT + col;
      float m = cmax[idx], s = csum[idx];
      float nM = fmaxf(M, m);
      Ssum = Ssum * EXP2F(M - nM) + s * EXP2F(m - nM);
      M = nM;
    }
    Qm[h][c] = M; Qs[h][c] = Ssum;
  }
  __syncthreads();
  if (tid < 128) {
    float M0 = Qm[0][tid], M1 = Qm[1][tid];
    float Mx = fmaxf(M0, M1);
    colmL[tid] = Mx;
    colsL[tid] = Qs[0][tid] * EXP2F(M0 - Mx) + Qs[1][tid] * EXP2F(M1 - Mx);
  }
  __syncthreads();

  // rows: 128 LSE partials (k_tile) + 64 exact count partials (k_gemm), then outputs
  if (tid < 32) {
    int row = cb * 32 + tid;
    float M = -3.0e38f, Ssum = 0.f;
    for (int k = 0; k < 128; ++k) {
      size_t idx = (size_t)k * N_V + row;
      float m = pmax[idx], s = psum[idx];
      float nM = fmaxf(M, m);
      Ssum = Ssum * EXP2F(M - nM) + s * EXP2F(m - nM);
      M = nM;
    }
    uint32_t c0 = 0, c1 = 0, c2 = 0, c3 = 0;
    for (int k = 0; k < 64; ++k) {
      uint4 cc = pcnt[(size_t)k * N_V + row];
      c0 += cc.x; c1 += cc.y; c2 += cc.z; c3 += cc.w;
    }
    float cm0 = colmL[tid * 4 + 0], cm1 = colmL[tid * 4 + 1];
    float cm2 = colmL[tid * 4 + 2], cm3 = colmL[tid * 4 + 3];
    float cs0 = colsL[tid * 4 + 0], cs1 = colsL[tid * 4 + 1];
    float cs2 = colsL[tid * 4 + 2], cs3 = colsL[tid * 4 + 3];
    float Mp = fmaxf(M, fmaxf(fmaxf(cm0, cm1), fmaxf(cm2, cm3)));
    float tot = Ssum * EXP2F(M - Mp)
              + cs0 * EXP2F(cm0 - Mp) + cs1 * EXP2F(cm1 - Mp)
              + cs2 * EXP2F(cm2 - Mp) + cs3 * EXP2F(cm3 - Mp);
    float ll = LN2 * (Mp + __log2f(tot)) - nom[row];
    float ar  = (float)(c0 + c1 + c2 + c3) * 0.25f;
    float r1  = (float)((c0 < 1u) + (c1 < 1u) + (c2 < 1u) + (c3 < 1u)) * 0.25f;
    float r5  = (float)((c0 < 5u) + (c1 < 5u) + (c2 < 5u) + (c3 < 5u)) * 0.25f;
    float r10 = (float)((c0 < 10u) + (c1 < 10u) + (c2 < 10u) + (c3 < 10u)) * 0.25f;
    float vals[5] = {ll, r1, r5, r10, ar};
#pragma unroll
    for (int k = 0; k < 5; ++k) {
      float vv = vals[k];
#pragma unroll
      for (int d = 1; d < 32; d <<= 1) vv += __shfl_xor(vv, d);
      if (tid == 0) atomicAdd(&out[k], vv * (1.0f / N_V));
    }
  }
}

extern "C" void kernel_launch(void* const* d_in, const int* in_sizes, int n_in,
                              void* d_out, int out_size, void* d_ws, size_t ws_size,
                              hipStream_t stream) {
  const float* v = (const float*)d_in[0];
  const float* t = (const float*)d_in[1];
  char* p = (char*)d_ws;
  unsigned short* Abf = (unsigned short*)p; p += (size_t)N_V * D_K * 2;     //   2 MB
  unsigned short* Bbf = (unsigned short*)p; p += (size_t)NT * D_K * 2;      //   8 MB
  float* thr  = (float*)p;    p += (size_t)N_V * 4 * 4;                     //  64 KB
  float* nom  = (float*)p;    p += (size_t)N_V * 4;                         //  16 KB
  unsigned short* S = (unsigned short*)p; p += (size_t)N_V * NT * 2;        // 128 MB
  float* pmax = (float*)p;    p += (size_t)128 * N_V * 4;                   //   2 MB
  float* psum = (float*)p;    p += (size_t)128 * N_V * 4;                   //   2 MB
  uint4* pcnt = (uint4*)p;    p += (size_t)64 * N_V * 16;                   //   4 MB
  float* cmaxp = (float*)p;   p += (size_t)64 * NT * 4;                     //   4 MB
  float* csump = (float*)p;   p += (size_t)64 * NT * 4;                     //   4 MB
  // total ws: ~154 MB

  k_prep<<<N_V / 4, 256, 0, stream>>>(v, t, Abf, Bbf, thr, nom, (float*)d_out);
  dim3 gg(NT / 256, N_V / 64);                    // 64 x 64
  k_gemm<<<gg, 256, 0, stream>>>(Abf, Bbf, thr, S, pcnt);
  dim3 gt(NT / 128, N_V / 64);                    // 128 x 64
  k_tile<<<gt, 256, 0, stream>>>(S, pmax, psum, cmaxp, csump);
  k_post<<<NT / 128, 256, 0, stream>>>(pmax, psum, pcnt, cmaxp, csump, nom, (float*)d_out);
}

// Round 11
// 202.035 us; speedup vs baseline: 1.1991x; 1.0857x over previous
//
#include <hip/hip_runtime.h>
#include <stdint.h>

#define N_V   4096
#define T_PER 4
#define NT    16384
#define D_K   256
#define SCALE 10.0f   // 1/temperature
#define LOG2E 1.44269504088896340736f
#define LN2   0.69314718055994530942f

#if defined(__has_builtin)
#if __has_builtin(__builtin_amdgcn_exp2f)
#define EXP2F(x) __builtin_amdgcn_exp2f(x)
#endif
#endif
#ifndef EXP2F
#define EXP2F(x) exp2f(x)
#endif

typedef __bf16 bf16x8 __attribute__((ext_vector_type(8)));
typedef float  f32x4  __attribute__((ext_vector_type(4)));

__device__ __forceinline__ unsigned short f2bf(float f) {
  uint32_t u = __float_as_uint(f);
  u = (u + 0x7fffu + ((u >> 16) & 1u)) >> 16;   // RNE
  return (unsigned short)u;
}

// ---------------- A: fused convert + diagonal dots (reads v,t exactly once) ---------------
// A-side bf16 carries SCALE*LOG2E so GEMM scores come out in log2 domain.
__global__ void k_prep(const float* __restrict__ v, const float* __restrict__ t,
                       unsigned short* __restrict__ Abf, unsigned short* __restrict__ Bbf,
                       float* __restrict__ thr, float* __restrict__ nom,
                       float* __restrict__ out) {
  const int tid = threadIdx.x, l = tid & 63, w = tid >> 6;
  const int i = blockIdx.x * 4 + w;            // one wave per video
  if (blockIdx.x == 0 && tid < 5) out[tid] = 0.0f;
  const float AS = SCALE * LOG2E;

  float4 a = ((const float4*)(v + (size_t)i * D_K))[l];
  ushort4 oa;
  oa.x = f2bf(a.x * AS); oa.y = f2bf(a.y * AS);
  oa.z = f2bf(a.z * AS); oa.w = f2bf(a.w * AS);
  ((ushort4*)(Abf + (size_t)i * D_K))[l] = oa;

  float tv[T_PER];
#pragma unroll
  for (int tt = 0; tt < T_PER; ++tt) {
    float4 b = ((const float4*)(t + (size_t)(i * T_PER + tt) * D_K))[l];
    ushort4 ob;
    ob.x = f2bf(b.x); ob.y = f2bf(b.y); ob.z = f2bf(b.z); ob.w = f2bf(b.w);
    ((ushort4*)(Bbf + (size_t)(i * T_PER + tt) * D_K))[l] = ob;
    float d = a.x * b.x + a.y * b.y + a.z * b.z + a.w * b.w;
#pragma unroll
    for (int s = 1; s < 64; s <<= 1) d += __shfl_xor(d, s);
    tv[tt] = d * SCALE;                        // natural-domain score
  }
  if (l == 0) {
    ((float4*)thr)[i] = make_float4(tv[0] * LOG2E, tv[1] * LOG2E,
                                    tv[2] * LOG2E, tv[3] * LOG2E);
    float m = fmaxf(fmaxf(tv[0], tv[1]), fmaxf(tv[2], tv[3]));
    float e = __expf(tv[0] - m) + __expf(tv[1] - m) + __expf(tv[2] - m) + __expf(tv[3] - m);
    nom[i] = m + __logf(e);
  }
}

// ---------------- B: r7-verbatim fused GEMM + LSE/rank epilogue ----------------------------
// Block = 64 rows x 256 cols; A staged to LDS once (single pre-loop barrier); B streams
// direct from global/L2, double-buffered (fine-grained vmcnt, no vmcnt(0) drains).
// Measured r7: 126us, absmax 6e-5, 321-TF-class (m102 shape-curve parity). Numerics: exact
// per-row/per-col maxes (r2/r3/r9 showed any shared-max scheme fails at sigma~230 log2).
__device__ __forceinline__ void gld16(const void* g, void* l) {
  __builtin_amdgcn_global_load_lds((const __attribute__((address_space(1))) void*)g,
                                   (__attribute__((address_space(3))) void*)l,
                                   16, 0, 0);
}

__global__ __launch_bounds__(256) void k_gemm(
    const unsigned short* __restrict__ Abf, const unsigned short* __restrict__ Bbf,
    const float* __restrict__ thr,
    float* __restrict__ pmax, float* __restrict__ psum, uint4* __restrict__ pcnt,
    float* __restrict__ cmax, float* __restrict__ csum) {
  __shared__ __align__(16) unsigned short As[64 * 256];   // 32 KB, swizzled full-K A tile
  __shared__ float4   thrS[64];
  __shared__ float    rowMw[4][64], rowEw[4][64];
  __shared__ uint32_t rowCw[4][64];

  const int ct = blockIdx.x, rt = blockIdx.y;
  const int row0 = rt * 64, col0 = ct * 256;
  const int tid = threadIdx.x;
  const int l = tid & 63, w = tid >> 6;
  const int quad = l >> 4, nl = l & 15;

  if (tid < 64) thrS[tid] = ((const float4*)thr)[row0 + tid];

  // stage A once: 32 groups of 1024 B; group g = (rowset rs = g>>2, k-span ks = g&3).
  // Lane l = lr*8+lc writes 16B chunk (lc^lr) of row lr at slot l*16 (XOR swizzle).
  const int lr = l >> 3, lc7 = l & 7, sc = lc7 ^ lr;
#pragma unroll
  for (int it = 0; it < 8; ++it) {
    int g = w * 8 + it;
    int rs = g >> 2, ks = g & 3;
    const unsigned short* ga = Abf + (size_t)(row0 + rs * 8 + lr) * D_K + ks * 64 + sc * 8;
    gld16(ga, (char*)As + g * 1024);
  }

  f32x4 acc[4][4];
#pragma unroll
  for (int i = 0; i < 4; ++i)
#pragma unroll
    for (int j = 0; j < 4; ++j) acc[i][j] = {0.f, 0.f, 0.f, 0.f};

  const unsigned short* pB[4];
#pragma unroll
  for (int j = 0; j < 4; ++j)
    pB[j] = Bbf + (size_t)(col0 + w * 64 + j * 16 + nl) * D_K + quad * 8;

  __syncthreads();   // the ONLY barrier before the epilogue

  bf16x8 bv[2][4];
#pragma unroll
  for (int j = 0; j < 4; ++j) bv[0][j] = *(const bf16x8*)(pB[j]);

#pragma unroll
  for (int c = 0; c < 8; ++c) {                 // 8 chunks of K=32
    const int cur = c & 1;
    if (c < 7) {
#pragma unroll
      for (int j = 0; j < 4; ++j)
        bv[cur ^ 1][j] = *(const bf16x8*)(pB[j] + (c + 1) * 32);
    }
    bf16x8 af[4];
#pragma unroll
    for (int i = 0; i < 4; ++i) {
      int r = i * 16 + nl;
      int rb = r & 7;
      int grp = (r >> 3) * 4 + (c >> 1);
      int cc = ((((c & 1) << 2) | quad) ^ rb);
      af[i] = *(const bf16x8*)((const char*)As + grp * 1024 + (rb * 8 + cc) * 16);
    }
#pragma unroll
    for (int i = 0; i < 4; ++i)
#pragma unroll
      for (int j = 0; j < 4; ++j)
        acc[i][j] = __builtin_amdgcn_mfma_f32_16x16x32_bf16(af[i], bv[cur][j],
                                                            acc[i][j], 0, 0, 0);
  }

  // ================= epilogue (scores in log2 domain) =================
  // C/D layout: col = nl, row = quad*4 + reg. Per-row/per-col maxes mandatory.

  uint32_t cnt[4][4];
#pragma unroll
  for (int i = 0; i < 4; ++i)
#pragma unroll
    for (int r = 0; r < 4; ++r) {
      float4 th = thrS[i * 16 + quad * 4 + r];
      uint32_t c = 0;
#pragma unroll
      for (int j = 0; j < 4; ++j) {
        float s = acc[i][j][r];
        c += (uint32_t)(s > th.x);
        c += (uint32_t)(s > th.y) << 8;
        c += (uint32_t)(s > th.z) << 16;
        c += (uint32_t)(s > th.w) << 24;
      }
      cnt[i][r] = c;
    }

  // row partials (wave's 64-col strip): per-row max (guarantees e >= 1), exp2-sum, count
#pragma unroll
  for (int i = 0; i < 4; ++i)
#pragma unroll
    for (int r = 0; r < 4; ++r) {
      float m = fmaxf(fmaxf(acc[i][0][r], acc[i][1][r]), fmaxf(acc[i][2][r], acc[i][3][r]));
#pragma unroll
      for (int d = 1; d < 16; d <<= 1) m = fmaxf(m, __shfl_xor(m, d));
      float e = EXP2F(acc[i][0][r] - m) + EXP2F(acc[i][1][r] - m)
              + EXP2F(acc[i][2][r] - m) + EXP2F(acc[i][3][r] - m);
      uint32_t c = cnt[i][r];
#pragma unroll
      for (int d = 1; d < 16; d <<= 1) { e += __shfl_xor(e, d); c += __shfl_xor(c, d); }
      if (nl == 0) {
        int row = i * 16 + quad * 4 + r;
        rowMw[w][row] = m; rowEw[w][row] = e; rowCw[w][row] = c;   // fields <= 64, no ovf
      }
    }

  // col partials: whole 64-row column lives in this wave -> direct global write
#pragma unroll
  for (int j = 0; j < 4; ++j) {
    float m = -3.0e38f;
#pragma unroll
    for (int i = 0; i < 4; ++i)
#pragma unroll
      for (int r = 0; r < 4; ++r) m = fmaxf(m, acc[i][j][r]);
    m = fmaxf(m, __shfl_xor(m, 16));
    m = fmaxf(m, __shfl_xor(m, 32));
    float e = 0.f;
#pragma unroll
    for (int i = 0; i < 4; ++i)
#pragma unroll
      for (int r = 0; r < 4; ++r) e += EXP2F(acc[i][j][r] - m);
    e += __shfl_xor(e, 16);
    e += __shfl_xor(e, 32);
    if (quad == 0) {
      int colg = col0 + w * 64 + j * 16 + nl;
      size_t gi = (size_t)rt * NT + colg;
      cmax[gi] = m; csum[gi] = e;
    }
  }
  __syncthreads();

  // combine the 4 col-strips per row (counts unpacked to 32-bit: 4x64 = 256 > 8-bit)
  if (tid < 64) {
    float M0 = rowMw[0][tid], M1 = rowMw[1][tid], M2 = rowMw[2][tid], M3 = rowMw[3][tid];
    float Mx = fmaxf(fmaxf(M0, M1), fmaxf(M2, M3));
    float Sx = rowEw[0][tid] * EXP2F(M0 - Mx) + rowEw[1][tid] * EXP2F(M1 - Mx)
             + rowEw[2][tid] * EXP2F(M2 - Mx) + rowEw[3][tid] * EXP2F(M3 - Mx);
    uint32_t c0 = 0, c1 = 0, c2 = 0, c3 = 0;
#pragma unroll
    for (int ww = 0; ww < 4; ++ww) {
      uint32_t cc = rowCw[ww][tid];
      c0 += cc & 0xffu; c1 += (cc >> 8) & 0xffu;
      c2 += (cc >> 16) & 0xffu; c3 += cc >> 24;
    }
    size_t gi = (size_t)ct * N_V + row0 + tid;
    pmax[gi] = Mx; psum[gi] = Sx; pcnt[gi] = make_uint4(c0, c1, c2, c3);
  }
}

// ---------------- C: fused col-reduce + row-reduce + loss/metrics --------------------------
// Block cb owns cols [cb*128, +128) AND rows [cb*32, +32): row r's needed col results
// (cols 4r..4r+3) are exactly in-range -> col results stay in LDS, no grid sync.
// (Structure verified in r9/r10; inputs here use r7's layouts: 64 ct row-partials with
// uint4 counts, 64 rt col-partials.)
__global__ void k_post(const float* __restrict__ pmax, const float* __restrict__ psum,
                       const uint4* __restrict__ pcnt,
                       const float* __restrict__ cmax, const float* __restrict__ csum,
                       const float* __restrict__ nom, float* __restrict__ out) {
  __shared__ float Qm[2][128], Qs[2][128];
  __shared__ float colmL[128], colsL[128];
  const int cb = blockIdx.x, tid = threadIdx.x;

  // cols: 64 rt-partials each, coalesced ([rt][col] layout)
  {
    int c = tid & 127, h = tid >> 7;
    size_t col = (size_t)cb * 128 + c;
    float M = -3.0e38f, Ssum = 0.f;
    for (int k = 0; k < 32; ++k) {
      size_t idx = (size_t)(h * 32 + k) * NT + col;
      float m = cmax[idx], s = csum[idx];
      float nM = fmaxf(M, m);
      Ssum = Ssum * EXP2F(M - nM) + s * EXP2F(m - nM);
      M = nM;
    }
    Qm[h][c] = M; Qs[h][c] = Ssum;
  }
  __syncthreads();
  if (tid < 128) {
    float M0 = Qm[0][tid], M1 = Qm[1][tid];
    float Mx = fmaxf(M0, M1);
    colmL[tid] = Mx;
    colsL[tid] = Qs[0][tid] * EXP2F(M0 - Mx) + Qs[1][tid] * EXP2F(M1 - Mx);
  }
  __syncthreads();

  // rows: 64 ct-partials (LSE + exact counts), then final loss/metrics
  if (tid < 32) {
    int row = cb * 32 + tid;
    float M = -3.0e38f, Ssum = 0.f;
    uint32_t c0 = 0, c1 = 0, c2 = 0, c3 = 0;
    for (int k = 0; k < 64; ++k) {
      size_t idx = (size_t)k * N_V + row;
      float m = pmax[idx], s = psum[idx];
      uint4 cc = pcnt[idx];
      float nM = fmaxf(M, m);
      Ssum = Ssum * EXP2F(M - nM) + s * EXP2F(m - nM);
      M = nM;
      c0 += cc.x; c1 += cc.y; c2 += cc.z; c3 += cc.w;
    }
    float cm0 = colmL[tid * 4 + 0], cm1 = colmL[tid * 4 + 1];
    float cm2 = colmL[tid * 4 + 2], cm3 = colmL[tid * 4 + 3];
    float cs0 = colsL[tid * 4 + 0], cs1 = colsL[tid * 4 + 1];
    float cs2 = colsL[tid * 4 + 2], cs3 = colsL[tid * 4 + 3];
    float Mp = fmaxf(M, fmaxf(fmaxf(cm0, cm1), fmaxf(cm2, cm3)));
    float tot = Ssum * EXP2F(M - Mp)
              + cs0 * EXP2F(cm0 - Mp) + cs1 * EXP2F(cm1 - Mp)
              + cs2 * EXP2F(cm2 - Mp) + cs3 * EXP2F(cm3 - Mp);
    float ll = LN2 * (Mp + __log2f(tot)) - nom[row];
    float ar  = (float)(c0 + c1 + c2 + c3) * 0.25f;
    float r1  = (float)((c0 < 1u) + (c1 < 1u) + (c2 < 1u) + (c3 < 1u)) * 0.25f;
    float r5  = (float)((c0 < 5u) + (c1 < 5u) + (c2 < 5u) + (c3 < 5u)) * 0.25f;
    float r10 = (float)((c0 < 10u) + (c1 < 10u) + (c2 < 10u) + (c3 < 10u)) * 0.25f;
    float vals[5] = {ll, r1, r5, r10, ar};
#pragma unroll
    for (int k = 0; k < 5; ++k) {
      float vv = vals[k];
#pragma unroll
      for (int d = 1; d < 32; d <<= 1) vv += __shfl_xor(vv, d);
      if (tid == 0) atomicAdd(&out[k], vv * (1.0f / N_V));
    }
  }
}

extern "C" void kernel_launch(void* const* d_in, const int* in_sizes, int n_in,
                              void* d_out, int out_size, void* d_ws, size_t ws_size,
                              hipStream_t stream) {
  const float* v = (const float*)d_in[0];
  const float* t = (const float*)d_in[1];
  char* p = (char*)d_ws;
  unsigned short* Abf = (unsigned short*)p; p += (size_t)N_V * D_K * 2;
  unsigned short* Bbf = (unsigned short*)p; p += (size_t)NT * D_K * 2;
  float* thr  = (float*)p;    p += (size_t)N_V * 4 * 4;
  float* nom  = (float*)p;    p += (size_t)N_V * 4;
  float* pmax = (float*)p;    p += (size_t)64 * N_V * 4;
  float* psum = (float*)p;    p += (size_t)64 * N_V * 4;
  uint4* pcnt = (uint4*)p;    p += (size_t)64 * N_V * 16;
  float* cmaxp = (float*)p;   p += (size_t)64 * NT * 4;
  float* csump = (float*)p;   p += (size_t)64 * NT * 4;
  // total ws: ~24 MB

  k_prep<<<N_V / 4, 256, 0, stream>>>(v, t, Abf, Bbf, thr, nom, (float*)d_out);
  dim3 g(NT / 256, N_V / 64);                     // ct x rt = 64 x 64
  k_gemm<<<g, 256, 0, stream>>>(Abf, Bbf, thr, pmax, psum, pcnt, cmaxp, csump);
  k_post<<<NT / 128, 256, 0, stream>>>(pmax, psum, pcnt, cmaxp, csump, nom, (float*)d_out);
}